// Round 1
// baseline (13873.434 us; speedup 1.0000x reference)
//
#include <hip/hip_runtime.h>
#include <hip/hip_fp16.h>
#include <math.h>

// ---------------- constants ----------------
constexpr int   N_   = 2048;
constexpr int   DF_  = 256;
constexpr int   J_   = 8;
constexpr int   ELLW_= 64;
constexpr int   M_   = 256;          // Chebyshev terms (degree 255)
constexpr float H_   = 1.01f;        // domain half-width  ([-0.01, 2.01])
constexpr float C0_  = 1.0f;         // domain center
constexpr float AF_  = 0.34657359027997264f;   // A = 3*ln(2)/6
constexpr float PI_F = 3.14159265358979323846f;

// ---------------- filter functions (match reference bit-for-bit-ish in fp32) --------
__device__ __forceinline__ float g_hat_f(float x) {
    float val = 0.5f + 0.5f * cosf(2.f * PI_F * (x / AF_ + 0.5f));
    return (x <= 0.f && x > -AF_) ? val : 0.f;
}
__device__ __forceinline__ float wavelet_f(float lamb, int j) {
    float lmin = expf(AF_ * ((j - 1) / 3.0f - 1.0f));
    float lam  = fmaxf(lamb, lmin);
    return g_hat_f(logf(lam) - AF_ * (j - 1) / 3.0f);
}
__device__ __forceinline__ float filter_eval(float lamb, int jf) {
    if (jf == 0) {
        float g3 = 0.f;
        for (int j = 2; j <= 8; ++j) { float w = wavelet_f(lamb, j); g3 += w * w; }
        return sqrtf(fmaxf(1.5f - g3, 0.f));
    }
    return wavelet_f(lamb, jf + 1);
}

// ---------------- setup kernels ----------------
__global__ __launch_bounds__(256) void deg_kernel(const float* __restrict__ W,
                                                  float* __restrict__ dh,
                                                  float* __restrict__ dr) {
    int i = blockIdx.x, t = threadIdx.x;
    const float4* row = (const float4*)(W + (size_t)i * N_);
    float s = 0.f;
    for (int c = t; c < N_ / 4; c += 256) { float4 v = row[c]; s += v.x + v.y + v.z + v.w; }
    __shared__ float red[256];
    red[t] = s; __syncthreads();
    for (int o = 128; o; o >>= 1) { if (t < o) red[t] += red[t + o]; __syncthreads(); }
    if (t == 0) {
        float deg = red[0];
        float dhi = 1.f / sqrtf(fmaxf(deg, 1.f));
        dh[i] = dhi;
        dr[i] = (dhi * dhi * deg - C0_) / H_;   // scaled diagonal of L-tilde
    }
}

__global__ __launch_bounds__(64) void ell_kernel(const float* __restrict__ W,
                                                 const float* __restrict__ dh,
                                                 int* __restrict__ cnt,
                                                 int* __restrict__ cols,
                                                 float* __restrict__ vals) {
    int i = blockIdx.x, lane = threadIdx.x;    // one wave per row
    const float* row = W + (size_t)i * N_;
    unsigned long long lt = (1ull << lane) - 1ull;
    int base = 0;
    float dhi = dh[i];
    for (int c = 0; c < N_; c += 64) {
        float v = row[c + lane];
        unsigned long long m = __ballot(v != 0.f);
        if (v != 0.f) {
            int pos = base + __popcll(m & lt);
            if (pos < ELLW_) {
                cols[i * ELLW_ + pos] = c + lane;
                vals[i * ELLW_ + pos] = dhi * dh[c + lane] / H_;
            }
        }
        base += __popcll(m);
    }
    if (lane == 0) cnt[i] = base < ELLW_ ? base : ELLW_;
}

__global__ __launch_bounds__(256) void coef_kernel(float* __restrict__ coefs) {
    __shared__ float fv[J_][M_];
    int t = threadIdx.x;                       // 256 threads, M_ == 256
    float theta = PI_F * (t + 0.5f) / M_;
    float lam = C0_ + H_ * cosf(theta);
    for (int j = 0; j < J_; ++j) fv[j][t] = filter_eval(lam, j);
    __syncthreads();
    for (int j = 0; j < J_; ++j) {
        float s = 0.f;
        for (int i = 0; i < M_; ++i)
            s += fv[j][i] * cosf(PI_F * t * (i + 0.5f) / M_);
        coefs[j * M_ + t] = s * ((t == 0 ? 1.f : 2.f) / M_);
    }
}

__global__ __launch_bounds__(256) void init_T(float* __restrict__ T0, float* __restrict__ T1,
                                              __half* __restrict__ S0, __half* __restrict__ S1,
                                              const int* __restrict__ cnt, const int* __restrict__ cols,
                                              const float* __restrict__ vals, const float* __restrict__ dr) {
    int i = blockIdx.x, t = threadIdx.x;
    size_t ro = (size_t)i * N_;
    for (int c = t * 4; c < N_; c += 1024) {
        *(float4*)(T0 + ro + c) = float4{0, 0, 0, 0};
        *(float4*)(T1 + ro + c) = float4{0, 0, 0, 0};
        if (S0) { *(ushort4*)(S0 + ro + c) = ushort4{0, 0, 0, 0};
                  *(ushort4*)(S1 + ro + c) = ushort4{0, 0, 0, 0}; }
    }
    __syncthreads();
    int n = cnt[i];
    if (t < n) {
        int c = cols[i * ELLW_ + t];
        float v = -vals[i * ELLW_ + t];
        T1[ro + c] = v;
        if (S1) S1[ro + c] = __float2half(v);
    }
    if (t == 0) {
        T0[ro + i] = 1.f;
        T1[ro + i] = dr[i];
        if (S0) { S0[ro + i] = __float2half(1.f); S1[ro + i] = __float2half(dr[i]); }
    }
}

// ---------------- Chebyshev recurrence step:  Tnext = 2*Ltilde*X - Tprev ----------------
__global__ __launch_bounds__(256) void cheb_step(const float* __restrict__ X,
                                                 const float* __restrict__ Tprev,
                                                 float* __restrict__ Tnext,
                                                 __half* __restrict__ slot,
                                                 const int* __restrict__ cnt,
                                                 const int* __restrict__ cols,
                                                 const float* __restrict__ vals,
                                                 const float* __restrict__ dr) {
    int i = blockIdx.x;
    int col = blockIdx.y * 1024 + threadIdx.x * 4;
    __shared__ int   scols[ELLW_];
    __shared__ float svals[ELLW_];
    int n = cnt[i];
    if (threadIdx.x < ELLW_) {
        scols[threadIdx.x] = cols[i * ELLW_ + threadIdx.x];
        svals[threadIdx.x] = vals[i * ELLW_ + threadIdx.x];
    }
    __syncthreads();
    float4 acc = {0, 0, 0, 0};
    for (int e = 0; e < n; ++e) {
        const float4 xv = *(const float4*)(X + (size_t)scols[e] * N_ + col);
        float v = svals[e];
        acc.x -= v * xv.x; acc.y -= v * xv.y; acc.z -= v * xv.z; acc.w -= v * xv.w;
    }
    float4 xs = *(const float4*)(X + (size_t)i * N_ + col);
    float d = dr[i];
    acc.x += d * xs.x; acc.y += d * xs.y; acc.z += d * xs.z; acc.w += d * xs.w;
    float4 tp = *(const float4*)(Tprev + (size_t)i * N_ + col);
    float4 o;
    o.x = 2.f * acc.x - tp.x; o.y = 2.f * acc.y - tp.y;
    o.z = 2.f * acc.z - tp.z; o.w = 2.f * acc.w - tp.w;
    *(float4*)(Tnext + (size_t)i * N_ + col) = o;
    if (slot) {
        __half2* sp = (__half2*)(slot + (size_t)i * N_ + col);
        sp[0] = __floats2half2_rn(o.x, o.y);
        sp[1] = __floats2half2_rn(o.z, o.w);
    }
}

// ---------------- group reduction:  G_j += sum_s b_{j,k0+s} * T_slot_s ----------------
__global__ __launch_bounds__(256) void reduce_half(const __half* __restrict__ slots, int nslot,
                                                   const float* __restrict__ coefs, int k0, int initG,
                                                   float* __restrict__ G) {
    const size_t NSQ = (size_t)N_ * N_;
    size_t idx = ((size_t)blockIdx.x * 256 + threadIdx.x) * 4;
    __shared__ float sc[J_ * 64];
    for (int x = threadIdx.x; x < J_ * nslot; x += 256) {
        int j = x / nslot, s = x - j * nslot;
        sc[j * 64 + s] = coefs[j * M_ + k0 + s];
    }
    __syncthreads();
    float4 g[J_];
#pragma unroll
    for (int j = 0; j < J_; ++j)
        g[j] = initG ? float4{0, 0, 0, 0} : *(const float4*)(G + (size_t)j * NSQ + idx);
    for (int s = 0; s < nslot; ++s) {
        const __half2* hp = (const __half2*)(slots + (size_t)s * NSQ + idx);
        float2 f0 = __half22float2(hp[0]);
        float2 f1 = __half22float2(hp[1]);
#pragma unroll
        for (int j = 0; j < J_; ++j) {
            float c = sc[j * 64 + s];
            g[j].x += c * f0.x; g[j].y += c * f0.y;
            g[j].z += c * f1.x; g[j].w += c * f1.y;
        }
    }
#pragma unroll
    for (int j = 0; j < J_; ++j) *(float4*)(G + (size_t)j * NSQ + idx) = g[j];
}

__global__ __launch_bounds__(256) void reduce_f32(const float* __restrict__ T,
                                                  const float* __restrict__ coefs, int k, int initG,
                                                  float* __restrict__ G) {
    const size_t NSQ = (size_t)N_ * N_;
    size_t idx = ((size_t)blockIdx.x * 256 + threadIdx.x) * 4;
    float4 tv = *(const float4*)(T + idx);
#pragma unroll
    for (int j = 0; j < J_; ++j) {
        float c = coefs[j * M_ + k];
        float* gp = G + (size_t)j * NSQ + idx;
        float4 g = initG ? float4{0, 0, 0, 0} : *(float4*)gp;
        g.x += c * tv.x; g.y += c * tv.y; g.z += c * tv.z; g.w += c * tv.w;
        *(float4*)gp = g;
    }
}

// ---------------- GEMM: C = G_all[8N x N] * B, fused |.| + column means ----------------
// MODE 0: B = f (row-major N x 256); store U1 = |C| and atomic col-sums into sum1[j*256+d]
// MODE 1: B = U1 block layout [8][N][256] viewed as N x 2048; col-sums into sum2[(b*8+j)*256+d]
template <int MODE>
__global__ __launch_bounds__(256) void gemm_kernel(const float* __restrict__ G,
                                                   const float* __restrict__ B,
                                                   float* __restrict__ U1,
                                                   float* __restrict__ colsum) {
    constexpr int BM = 128, BN = 128, BK = 16;
    int ntile = blockIdx.x, mtile = blockIdx.y;
    int tid = threadIdx.x;
    int tm = tid >> 4, tn = tid & 15;
    __shared__ float As[BK][BM + 4];
    __shared__ float Bs[BK][BN + 4];
    int gm0  = mtile * BM;
    int jblk = gm0 / N_;
    int i0   = gm0 % N_;
    const float* Abase = G + (size_t)jblk * N_ * N_ + (size_t)i0 * N_;
    int n0 = ntile * BN;
    float acc[8][8] = {};
    for (int k0 = 0; k0 < N_; k0 += BK) {
#pragma unroll
        for (int l = 0; l < 2; ++l) {
            int fid = tid + l * 256;
            int row = fid >> 2, kq = (fid & 3) << 2;
            float4 a = *(const float4*)(Abase + (size_t)row * N_ + k0 + kq);
            As[kq + 0][row] = a.x; As[kq + 1][row] = a.y;
            As[kq + 2][row] = a.z; As[kq + 3][row] = a.w;
        }
#pragma unroll
        for (int l = 0; l < 2; ++l) {
            int fid = tid + l * 256;
            int row = fid >> 5, c4 = (fid & 31) << 2;
            int gc = n0 + c4;
            const float* bp;
            if (MODE == 0) bp = B + (size_t)(k0 + row) * DF_ + gc;
            else bp = B + (size_t)(gc >> 8) * ((size_t)N_ * DF_) + (size_t)(k0 + row) * DF_ + (gc & 255);
            *(float4*)&Bs[row][c4] = *(const float4*)bp;
        }
        __syncthreads();
#pragma unroll
        for (int kk = 0; kk < BK; ++kk) {
            float ra[8], rb[8];
#pragma unroll
            for (int u = 0; u < 8; ++u) ra[u] = As[kk][tm * 8 + u];
#pragma unroll
            for (int v = 0; v < 8; ++v) rb[v] = Bs[kk][tn * 8 + v];
#pragma unroll
            for (int u = 0; u < 8; ++u)
#pragma unroll
                for (int v = 0; v < 8; ++v) acc[u][v] += ra[u] * rb[v];
        }
        __syncthreads();
    }
    // epilogue: abs, optional store, column sums
    __shared__ float sums[16][BN + 4];
    float csum[8];
#pragma unroll
    for (int v = 0; v < 8; ++v) csum[v] = 0.f;
#pragma unroll
    for (int u = 0; u < 8; ++u) {
        int gm = gm0 + tm * 8 + u;
        int i = gm & (N_ - 1);
#pragma unroll
        for (int v = 0; v < 8; ++v) {
            float val = fabsf(acc[u][v]);
            csum[v] += val;
            if (MODE == 0) {
                int gc = n0 + tn * 8 + v;
                U1[(size_t)jblk * N_ * DF_ + (size_t)i * DF_ + gc] = val;
            }
        }
    }
#pragma unroll
    for (int v = 0; v < 8; ++v) sums[tm][tn * 8 + v] = csum[v];
    __syncthreads();
    if (tid < BN) {
        float s = 0.f;
        for (int r = 0; r < 16; ++r) s += sums[r][tid];
        int gc = n0 + tid;
        if (MODE == 0) atomicAdd(&colsum[jblk * DF_ + gc], s);
        else atomicAdd(&colsum[((gc >> 8) * 8 + jblk) * DF_ + (gc & 255)], s);
    }
}

__global__ __launch_bounds__(256) void fmean_kernel(const float* __restrict__ f, float* __restrict__ out) {
    int d = threadIdx.x;
    float s = 0.f;
    for (int n = 0; n < N_; ++n) s += f[(size_t)n * DF_ + d];
    out[d] = s * (1.f / N_);
}

__global__ __launch_bounds__(256) void finalize_kernel(const float* __restrict__ sum1,
                                                       const float* __restrict__ sum2,
                                                       float* __restrict__ out) {
    int idx = blockIdx.x * 256 + threadIdx.x;
    if (idx < 2048)  out[256 + idx]  = sum1[idx] * (1.f / N_);
    if (idx < 16384) out[2304 + idx] = sum2[idx] * (1.f / N_);
}

// ---------------- host orchestration ----------------
extern "C" void kernel_launch(void* const* d_in, const int* in_sizes, int n_in,
                              void* d_out, int out_size, void* d_ws, size_t ws_size,
                              hipStream_t stream) {
    (void)in_sizes; (void)n_in;
    const float* W = (const float*)d_in[0];
    const float* f = (const float*)d_in[1];
    float* out = (float*)d_out;
    char* base = (char*)d_ws;
    size_t off = 0;
    auto take = [&](size_t bytes) -> char* {
        off = (off + 255) & ~(size_t)255;
        char* p = base + off; off += bytes; return p;
    };
    const size_t NSQ = (size_t)N_ * N_;
    float* dh    = (float*)take((size_t)N_ * 4);
    float* dr    = (float*)take((size_t)N_ * 4);
    int*   cnt   = (int*)take((size_t)N_ * 4);
    int*   cols  = (int*)take((size_t)N_ * ELLW_ * 4);
    float* vals  = (float*)take((size_t)N_ * ELLW_ * 4);
    float* coefs = (float*)take((size_t)J_ * M_ * 4);
    float* sum1  = (float*)take(2048 * 4);
    float* sum2  = (float*)take(16384 * 4);
    float* T0 = (float*)take(NSQ * 4);
    float* T1 = (float*)take(NSQ * 4);
    float* T2 = (float*)take(NSQ * 4);
    float* G  = (float*)take(NSQ * 4 * J_);
    float* U1 = (float*)take((size_t)J_ * N_ * DF_ * 4);
    off = (off + 255) & ~(size_t)255;
    if (ws_size < off) {  // workspace cannot even hold the fixed part: fail cleanly
        hipMemsetAsync(d_out, 0, (size_t)out_size * 4, stream);
        return;
    }
    const size_t slotBytes = NSQ * 2;  // fp16 N x N
    long long rem = (long long)ws_size - (long long)off;
    int g = (int)(rem / (long long)slotBytes);
    if (g > 64) g = 64;
    __half* slots = (__half*)(base + off);
    bool f16path = g >= 3;

    deg_kernel<<<N_, 256, 0, stream>>>(W, dh, dr);
    ell_kernel<<<N_, 64, 0, stream>>>(W, dh, cnt, cols, vals);
    coef_kernel<<<1, 256, 0, stream>>>(coefs);
    hipMemsetAsync(sum1, 0, 2048 * 4, stream);
    hipMemsetAsync(sum2, 0, 16384 * 4, stream);
    init_T<<<N_, 256, 0, stream>>>(T0, T1,
                                   f16path ? slots : (__half*)nullptr,
                                   f16path ? slots + NSQ : (__half*)nullptr,
                                   cnt, cols, vals, dr);
    float* Tb[3] = {T0, T1, T2};
    if (f16path) {
        int group_start = 0;
        for (int k = 2; k < M_; ++k) {
            cheb_step<<<dim3(N_, 2), 256, 0, stream>>>(
                Tb[(k - 1) % 3], Tb[(k - 2) % 3], Tb[k % 3],
                slots + (size_t)(k - group_start) * NSQ, cnt, cols, vals, dr);
            if (k - group_start + 1 == g || k == M_ - 1) {
                reduce_half<<<4096, 256, 0, stream>>>(slots, k - group_start + 1, coefs,
                                                      group_start, group_start == 0 ? 1 : 0, G);
                group_start = k + 1;
            }
        }
    } else {
        reduce_f32<<<4096, 256, 0, stream>>>(T0, coefs, 0, 1, G);
        reduce_f32<<<4096, 256, 0, stream>>>(T1, coefs, 1, 0, G);
        for (int k = 2; k < M_; ++k) {
            cheb_step<<<dim3(N_, 2), 256, 0, stream>>>(
                Tb[(k - 1) % 3], Tb[(k - 2) % 3], Tb[k % 3],
                (__half*)nullptr, cnt, cols, vals, dr);
            reduce_f32<<<4096, 256, 0, stream>>>(Tb[k % 3], coefs, k, 0, G);
        }
    }
    gemm_kernel<0><<<dim3(2, 128), 256, 0, stream>>>(G, f, U1, sum1);
    gemm_kernel<1><<<dim3(16, 128), 256, 0, stream>>>(G, U1, nullptr, sum2);
    fmean_kernel<<<1, 256, 0, stream>>>(f, out);
    finalize_kernel<<<64, 256, 0, stream>>>(sum1, sum2, out);
}